// Round 7
// baseline (148.313 us; speedup 1.0000x reference)
//
#include <hip/hip_runtime.h>
#include <cstdio>

// B=32, Cin=128, S=8192, H=4, Hc=32, M=64, Cout=128
#define S_LEN 8192
#define NM 64

typedef short s8v __attribute__((ext_vector_type(8)));   // 8 bf16
typedef float f4  __attribute__((ext_vector_type(4)));
typedef _Float16 h8 __attribute__((ext_vector_type(8))); // 8 fp16 (MFMA f16 frag)
typedef _Float16 h4v __attribute__((ext_vector_type(4)));

static __device__ inline unsigned short f2bf(float f) {  // RNE fp32->bf16
    unsigned int u = __builtin_bit_cast(unsigned int, f);
    u = (u + 0x7FFFu + ((u >> 16) & 1u)) >> 16;
    return (unsigned short)u;
}
static __device__ inline float bf2f(unsigned short h) {
    unsigned int u = ((unsigned int)h) << 16;
    return __builtin_bit_cast(float, u);
}

// K3-side swizzle (unchanged): [128 r][32 k] tile, XOR k-bits 3..4 with (r>>1)&3
#define SW32(r, k) (((r) * 32) + ((k) ^ ((((r) >> 1) & 3) << 3)))

static __device__ __forceinline__ void glds16(const void* g, void* l) {
    __builtin_amdgcn_global_load_lds(
        (const __attribute__((address_space(1))) unsigned int*)g,
        (__attribute__((address_space(3))) unsigned int*)l, 16, 0, 0);
}

// ---------------- table gen ----------------
// T1 image (K3's B^T, UNCHANGED): (s,k) k=2m|2m+1; img[(sb*4+kc)*4096 + SW32(s&127,k&31)]
__global__ __launch_bounds__(256) void gen_t1_img(short* __restrict__ Th,
                                                  short* __restrict__ Tl) {
    int tid = blockIdx.x * 256 + threadIdx.x;     // 1M
    int tile = tid >> 12;
    int sb = tile >> 2, kc = tile & 3;
    int us = tid & 4095;
    int ls = us >> 5, kx = us & 31;
    int lk = kx ^ (((ls >> 1) & 3) << 3);
    int s = sb * 128 + ls;
    int k = kc * 32 + lk;
    int m = k >> 1;
    int p = (m * s) & (S_LEN - 1);
    float ang = (float)p * (6.28318530717958647692f / (float)S_LEN);
    float sn, cs; sincosf(ang, &sn, &cs);
    float v = (k & 1) ? -sn : cs;                 // k=1: -sin(0)=0 -> irfft drops Im(DC)
    unsigned short h = f2bf(v);
    Th[tid] = (short)h;
    Tl[tid] = (short)f2bf(v - bf2f(h));
}

// T2f image (K1's B^T, fp16 single): 64 tiles (k-steps of 128) x [128 c][128 k].
// fp16-unit idx within tile: c*128 + ((k>>3)^(c&15))*8 + (k&7). val=(c&1)?-sin:cos(2pi m kg/S).
__global__ __launch_bounds__(256) void gen_t2f(_Float16* __restrict__ T2f) {
    int tid = blockIdx.x * 256 + threadIdx.x;     // 1M
    int tile = tid >> 14;
    int us = tid & 16383;
    int c = us >> 7, kx = us & 127;
    int k = ((((kx >> 3) ^ (c & 15)) << 3) | (kx & 7));   // invert slot swizzle
    int kg = tile * 128 + k;
    int m = c >> 1;
    int p = (m * kg) & (S_LEN - 1);
    float ang = (float)p * (6.28318530717958647692f / (float)S_LEN);
    float sn, cs; sincosf(ang, &sn, &cs);
    float v = (c & 1) ? -sn : cs;
    T2f[tid] = (_Float16)v;
}

// ---------------- K1: X[4096][128] = x * B1, streaming, counted-vmcnt pipeline ----------------
// 256 blocks (1/CU), 512 thr (8 waves). Block owns 16 rows, full K=8192, BK=128, 64 steps.
// A: fp32->fp16 hi/lo split (2-pass MFMA); B: fp16 single via global_load_lds (pre-swizzled).
__global__ __launch_bounds__(512, 2) void dft_fwd_mfma(const float* __restrict__ x,
        const _Float16* __restrict__ T2f, float* __restrict__ X) {
    __shared__ _Float16 abh[2][16 * 128], abl[2][16 * 128];  // 4KB per buf -> 16KB
    __shared__ _Float16 bb[2][128 * 128];                    // 32KB per buf -> 64KB
    const int t = threadIdx.x;
    const int lane = t & 63, w = t >> 6;          // 8 waves
    const int rl = lane & 15, kq = lane >> 4;     // frag row/col + k-quad
    const int cB = w * 16 + rl;                   // this wave's output col for B frag
    const int row0 = blockIdx.x * 16;
    // A staging coords: 512 thr cover 16 rows x 128 floats (4 floats/thread)
    const int rA = t >> 5;                        // 0..15
    const int cA = (t & 31) * 4;                  // 0..124
    const size_t xbase = (size_t)(row0 + rA) * S_LEN + cA;
    const int usA = rA * 128 + ((((cA >> 3) ^ rA) & 15) << 3) + (cA & 7);
    const int wB = w * 4096 + lane * 16;          // byte offset for B glds

    f4 acc = (f4){0.f, 0.f, 0.f, 0.f};
    f4 avA, avB;

    #define GLB(kc, NXT) {                                                         \
        const char* gsrc = (const char*)T2f + (size_t)(kc) * 32768 + wB;           \
        char* ldst = (char*)&bb[NXT][0] + w * 4096;                                \
        glds16(gsrc,        ldst);                                                 \
        glds16(gsrc + 1024, ldst + 1024);                                          \
        glds16(gsrc + 2048, ldst + 2048);                                          \
        glds16(gsrc + 3072, ldst + 3072); }

    #define LA(kc, AV) AV = *(const f4*)&x[xbase + (size_t)(kc) * 128];

    #define CV(AV, NXT) { h4v hv, lv;                                              \
        _Pragma("unroll")                                                          \
        for (int e = 0; e < 4; ++e) {                                              \
            float f = AV[e]; _Float16 hh = (_Float16)f;                            \
            hv[e] = hh; lv[e] = (_Float16)(f - (float)hh);                         \
        }                                                                          \
        *(h4v*)&abh[NXT][usA] = hv;                                                \
        *(h4v*)&abl[NXT][usA] = lv; }

    #define MM(CUR) {                                                              \
        _Pragma("unroll")                                                          \
        for (int ksl = 0; ksl < 4; ++ksl) {                                        \
            const int sl = ((((ksl << 2) + kq) ^ rl) << 3);                        \
            h8 Ah = *(const h8*)&abh[CUR][rl * 128 + sl];                          \
            h8 Al = *(const h8*)&abl[CUR][rl * 128 + sl];                          \
            h8 Bf = *(const h8*)&bb[CUR][cB * 128 + sl];                           \
            acc = __builtin_amdgcn_mfma_f32_16x16x32_f16(Ah, Bf, acc, 0, 0, 0);    \
            acc = __builtin_amdgcn_mfma_f32_16x16x32_f16(Al, Bf, acc, 0, 0, 0);    \
        } }

    // One barrier/step; B-glds issued FIRST so vmcnt(1) leaves only the (newest) A-load.
    #define STEP(SC, AVC, AVN, CUR, NXT)                                           \
        GLB((SC) + 1, NXT);                                                        \
        __builtin_amdgcn_sched_barrier(0);                                         \
        LA(((SC) + 2) & 63, AVN);                                                  \
        CV(AVC, NXT);                                                              \
        MM(CUR);                                                                   \
        asm volatile("s_waitcnt lgkmcnt(0)" ::: "memory");                         \
        asm volatile("s_waitcnt vmcnt(1)" ::: "memory");                           \
        __builtin_amdgcn_sched_barrier(0);                                         \
        __builtin_amdgcn_s_barrier();                                              \
        __builtin_amdgcn_sched_barrier(0);

    // prologue: stage step 0 (conv's implicit wait drains B0 too - prologue only)
    GLB(0, 0);
    __builtin_amdgcn_sched_barrier(0);
    LA(0, avA);
    LA(1, avB);
    CV(avA, 0);
    asm volatile("s_waitcnt lgkmcnt(0)" ::: "memory");
    __builtin_amdgcn_sched_barrier(0);
    __builtin_amdgcn_s_barrier();
    __builtin_amdgcn_sched_barrier(0);

    for (int s = 0; s < 62; s += 2) {
        STEP(s,     avB, avA, 0, 1)
        STEP(s + 1, avA, avB, 1, 0)
    }
    STEP(62, avB, avA, 0, 1)      // A((64)&63)=A(0) is a harmless dummy prefetch
    MM(1);                        // tail step 63

    // D layout: col=lane&15, row=(lane>>4)*4+reg
    #pragma unroll
    for (int r = 0; r < 4; ++r)
        X[(size_t)(row0 + kq * 4 + r) * 128 + w * 16 + rl] = acc[r];
}

// ---------------- K2: mode contraction -> C2 image (pre-swizzled bf16 hi/lo) ----------------
__global__ __launch_bounds__(256) void mode_contract(const float* __restrict__ X,
        const float* __restrict__ w_real, const float* __restrict__ w_imag,
        short* __restrict__ C2h, short* __restrict__ C2l) {
    __shared__ float xr[32][128], xi[32][128];
    __shared__ float wr[128][32], wi[128][32];
    const int m = blockIdx.x, h = blockIdx.y, t = threadIdx.x;
    #pragma unroll
    for (int it = 0; it < 16; ++it) {
        int li = t + it * 256;       // 0..4095
        int b = li >> 7, i = li & 127;
        const float2 v = *(const float2*)&X[(size_t)(b * 128 + i) * 128 + 2 * m];
        xr[b][i] = v.x; xi[b][i] = v.y;
        int i2 = li >> 5, o = li & 31;
        size_t off = ((size_t)((h * 128 + i2) * 32 + o)) * NM + m;
        wr[i2][o] = w_real[off];
        wi[i2][o] = w_imag[off];
    }
    __syncthreads();
    const int o = t & 31;
    const int b0 = (t >> 5) * 4;
    float re[4] = {0.f, 0.f, 0.f, 0.f}, im[4] = {0.f, 0.f, 0.f, 0.f};
    for (int i = 0; i < 128; ++i) {
        float wrv = wr[i][o], wiv = wi[i][o];
        #pragma unroll
        for (int j = 0; j < 4; ++j) {
            float a = xr[b0 + j][i], c = xi[b0 + j][i];
            re[j] += a * wrv - c * wiv;
            im[j] += a * wiv + c * wrv;
        }
    }
    const float alpha = (m == 0) ? (1.0f / (float)S_LEN) : (2.0f / (float)S_LEN);
    const int kc = m >> 4;
    const int lk = (2 * m) & 31;
    #pragma unroll
    for (int j = 0; j < 4; ++j) {
        int row = (b0 + j) * 128 + h * 32 + o;
        float vr = alpha * re[j], vi = alpha * im[j];
        unsigned short hr = f2bf(vr), hi_ = f2bf(vi);
        float lr = vr - bf2f(hr), li_ = vi - bf2f(hi_);
        int rb = row >> 7, lr_ = row & 127;
        size_t ui = ((size_t)(rb * 4 + kc) * 4096 + SW32(lr_, lk)) >> 1;   // uint index
        ((unsigned int*)C2h)[ui] = ((unsigned int)hi_ << 16) | hr;
        ((unsigned int*)C2l)[ui] = ((unsigned int)f2bf(li_) << 16) | f2bf(lr);
    }
}

// ---------------- K3: y = C2[4096][128] * Basis[128][8192], dbuf DMA pipeline ----------------
__global__ __launch_bounds__(256, 2) void idft_mfma(const short* __restrict__ C2h,
        const short* __restrict__ C2l, const short* __restrict__ T1h,
        const short* __restrict__ T1l, float* __restrict__ y) {
    __shared__ short ah[2][4096], al[2][4096];
    __shared__ short bh[2][4096], bl[2][4096];
    const int t = threadIdx.x;
    const int lane = t & 63, wid = t >> 6;
    const int wm = (wid >> 1) * 64, wn = (wid & 1) * 64;
    const int sb = blockIdx.x;                    // col block (s), 0..63
    const int rb = blockIdx.y;                    // row block, 0..31
    f4 acc[4][4];
    #pragma unroll
    for (int i = 0; i < 4; ++i)
        #pragma unroll
        for (int j = 0; j < 4; ++j) acc[i][j] = (f4){0.f, 0.f, 0.f, 0.f};

    #define DMA3(kc, buf)  {                                                       \
        const size_t ta = (size_t)(rb * 4 + (kc)) * 8192;                          \
        const size_t tb = (size_t)(sb * 4 + (kc)) * 8192;                          \
        const int wo = wid * 2048 + lane * 16;                                     \
        glds16((const char*)C2h + ta + wo,        (char*)&ah[buf][0] + wid * 2048);        \
        glds16((const char*)C2h + ta + wo + 1024, (char*)&ah[buf][0] + wid * 2048 + 1024); \
        glds16((const char*)C2l + ta + wo,        (char*)&al[buf][0] + wid * 2048);        \
        glds16((const char*)C2l + ta + wo + 1024, (char*)&al[buf][0] + wid * 2048 + 1024); \
        glds16((const char*)T1h + tb + wo,        (char*)&bh[buf][0] + wid * 2048);        \
        glds16((const char*)T1h + tb + wo + 1024, (char*)&bh[buf][0] + wid * 2048 + 1024); \
        glds16((const char*)T1l + tb + wo,        (char*)&bl[buf][0] + wid * 2048);        \
        glds16((const char*)T1l + tb + wo + 1024, (char*)&bl[buf][0] + wid * 2048 + 1024); }

    DMA3(0, 0);
    __syncthreads();
    #pragma unroll
    for (int kc = 0; kc < 4; ++kc) {
        const int cur = kc & 1;
        if (kc < 3) DMA3(kc + 1, cur ^ 1);
        {
            const int kk = (lane >> 4) * 8, rl = lane & 15;
            s8v Ah[4], Al[4], Bh[4], Bl[4];
            #pragma unroll
            for (int mf = 0; mf < 4; ++mf) {
                int us = SW32(wm + mf * 16 + rl, kk);
                Ah[mf] = *(const s8v*)&ah[cur][us];
                Al[mf] = *(const s8v*)&al[cur][us];
            }
            #pragma unroll
            for (int nf = 0; nf < 4; ++nf) {
                int us = SW32(wn + nf * 16 + rl, kk);
                Bh[nf] = *(const s8v*)&bh[cur][us];
                Bl[nf] = *(const s8v*)&bl[cur][us];
            }
            #pragma unroll
            for (int mf = 0; mf < 4; ++mf)
                #pragma unroll
                for (int nf = 0; nf < 4; ++nf)
                    acc[mf][nf] = __builtin_amdgcn_mfma_f32_16x16x32_bf16(Ah[mf], Bh[nf], acc[mf][nf], 0, 0, 0);
            #pragma unroll
            for (int mf = 0; mf < 4; ++mf)
                #pragma unroll
                for (int nf = 0; nf < 4; ++nf)
                    acc[mf][nf] = __builtin_amdgcn_mfma_f32_16x16x32_bf16(Al[mf], Bh[nf], acc[mf][nf], 0, 0, 0);
            #pragma unroll
            for (int mf = 0; mf < 4; ++mf)
                #pragma unroll
                for (int nf = 0; nf < 4; ++nf)
                    acc[mf][nf] = __builtin_amdgcn_mfma_f32_16x16x32_bf16(Ah[mf], Bl[nf], acc[mf][nf], 0, 0, 0);
        }
        __syncthreads();
    }
    #pragma unroll
    for (int mf = 0; mf < 4; ++mf) {
        int rr = rb * 128 + wm + mf * 16 + (lane >> 4) * 4;
        #pragma unroll
        for (int nf = 0; nf < 4; ++nf) {
            int c = sb * 128 + wn + nf * 16 + (lane & 15);
            #pragma unroll
            for (int r = 0; r < 4; ++r)
                __builtin_nontemporal_store(acc[mf][nf][r], &y[(size_t)(rr + r) * S_LEN + c]);
        }
    }
}

extern "C" void kernel_launch(void* const* d_in, const int* in_sizes, int n_in,
                              void* d_out, int out_size, void* d_ws, size_t ws_size,
                              hipStream_t stream) {
    const float* x      = (const float*)d_in[0];
    const float* w_real = (const float*)d_in[1];
    const float* w_imag = (const float*)d_in[2];
    float* y = (float*)d_out;

    const size_t TBL = (size_t)S_LEN * 128;       // 1M elems per table half
    char* w0 = (char*)d_ws;
    short* T1h     = (short*)w0;                  // 2MB each half
    short* T1l     = T1h + TBL;
    _Float16* T2f  = (_Float16*)(T1l + TBL);      // 2MB fp16 single
    float* X       = (float*)(T2f + TBL);         // 2MB
    short* C2h     = (short*)(X + (size_t)4096 * 128);
    short* C2l     = C2h + (size_t)4096 * 128;
    const size_t TOTAL = (size_t)((char*)(C2l + (size_t)4096 * 128) - w0);  // 12MB
    if (ws_size < TOTAL) {
        fprintf(stderr, "kernel_launch: ws too small (%zu < %zu bytes)\n", ws_size, TOTAL);
        return;
    }

    gen_t1_img<<<(S_LEN * 128) / 256, 256, 0, stream>>>(T1h, T1l);
    gen_t2f<<<(S_LEN * 128) / 256, 256, 0, stream>>>(T2f);
    dft_fwd_mfma<<<4096 / 16, 512, 0, stream>>>(x, T2f, X);
    mode_contract<<<dim3(NM, 4), 256, 0, stream>>>(X, w_real, w_imag, C2h, C2l);
    idft_mfma<<<dim3(S_LEN / 128, 4096 / 128), 256, 0, stream>>>(C2h, C2l, T1h, T1l, y);
}

// Round 8
// 129.936 us; speedup vs baseline: 1.1414x; 1.1414x over previous
//
#include <hip/hip_runtime.h>
#include <cstdio>

// B=32, Cin=128, S=8192, H=4, Hc=32, M=64, Cout=128
#define S_LEN 8192
#define NM 64

typedef short s8v __attribute__((ext_vector_type(8)));   // 8 bf16
typedef float f4  __attribute__((ext_vector_type(4)));
typedef _Float16 h8 __attribute__((ext_vector_type(8))); // 8 fp16 (MFMA f16 frag)
typedef _Float16 h4v __attribute__((ext_vector_type(4)));

static __device__ inline unsigned short f2bf(float f) {  // RNE fp32->bf16
    unsigned int u = __builtin_bit_cast(unsigned int, f);
    u = (u + 0x7FFFu + ((u >> 16) & 1u)) >> 16;
    return (unsigned short)u;
}
static __device__ inline float bf2f(unsigned short h) {
    unsigned int u = ((unsigned int)h) << 16;
    return __builtin_bit_cast(float, u);
}

// K3-side swizzle: [128 r][32 k] tile, XOR k-bits 3..4 with (r>>1)&3
#define SW32(r, k) (((r) * 32) + ((k) ^ ((((r) >> 1) & 3) << 3)))

static __device__ __forceinline__ void glds16(const void* g, void* l) {
    __builtin_amdgcn_global_load_lds(
        (const __attribute__((address_space(1))) unsigned int*)g,
        (__attribute__((address_space(3))) unsigned int*)l, 16, 0, 0);
}

// ---------------- table gen ----------------
// T1 image (K3's B^T): (s,k) k=2m|2m+1; img[(sb*4+kc)*4096 + SW32(s&127,k&31)]
__global__ __launch_bounds__(256) void gen_t1_img(short* __restrict__ Th,
                                                  short* __restrict__ Tl) {
    int tid = blockIdx.x * 256 + threadIdx.x;     // 1M
    int tile = tid >> 12;
    int sb = tile >> 2, kc = tile & 3;
    int us = tid & 4095;
    int ls = us >> 5, kx = us & 31;
    int lk = kx ^ (((ls >> 1) & 3) << 3);
    int s = sb * 128 + ls;
    int k = kc * 32 + lk;
    int m = k >> 1;
    int p = (m * s) & (S_LEN - 1);
    float ang = (float)p * (6.28318530717958647692f / (float)S_LEN);
    float sn, cs; sincosf(ang, &sn, &cs);
    float v = (k & 1) ? -sn : cs;                 // k=1: -sin(0)=0 -> irfft drops Im(DC)
    unsigned short h = f2bf(v);
    Th[tid] = (short)h;
    Tl[tid] = (short)f2bf(v - bf2f(h));
}

// Bimg (K1's B, FRAGMENT order): [w32 256][cf 8][lane 64][8 fp16] = 2MB.
// lane=(kq<<4)|rl -> col=cf*16+rl, k=w32*32+kq*8+e; val=(col&1)?-sin:cos(2pi m k/S).
__global__ __launch_bounds__(256) void gen_b_img(_Float16* __restrict__ Bimg) {
    int tid = blockIdx.x * 256 + threadIdx.x;     // 1M
    int e = tid & 7;
    int lane = (tid >> 3) & 63;
    int cf = (tid >> 9) & 7;
    int w32 = tid >> 12;
    int rl = lane & 15, kq = lane >> 4;
    int col = cf * 16 + rl;
    int m = col >> 1;
    int k = w32 * 32 + kq * 8 + e;
    int p = (m * k) & (S_LEN - 1);
    float ang = (float)p * (6.28318530717958647692f / (float)S_LEN);
    float sn, cs; sincosf(ang, &sn, &cs);
    Bimg[tid] = (_Float16)((col & 1) ? -sn : cs);
}

// ---------------- K1: P[ks] = x * B1, barrier-clean streaming MFMA ----------------
// 512 blocks (2/CU) x 512 thr. Block: 16 rows x K=4096 (32 steps of 128).
// A: fp32->fp16 hi/lo, LDS dbuf, prefetch distance 2. B: regs direct from L2 image.
// NO vm-waits at barriers (no glds in this kernel).
#define NSTEP 32
__global__ __launch_bounds__(512, 4) void dft_fwd_mfma(const float* __restrict__ x,
        const _Float16* __restrict__ Bimg, float* __restrict__ P) {
    __shared__ _Float16 abh[2][16 * 128], abl[2][16 * 128];  // 4KB each -> 16KB
    const int t = threadIdx.x;
    const int lane = t & 63, w = t >> 6;          // 8 waves; wave w owns colfrag w
    const int rl = lane & 15, kq = lane >> 4;
    const int row0 = blockIdx.x * 16;
    const int ks = blockIdx.y;                    // 0..1
    // A staging coords: 512 thr cover 16 rows x 128 fp32 (4 per thread)
    const int rA = t >> 5, cA = (t & 31) * 4;
    const size_t xrow = (size_t)(row0 + rA) * S_LEN + (size_t)ks * (S_LEN / 2) + cA;
    const int usA = rA * 128 + ((((cA >> 3) ^ rA) & 15) << 3) + (cA & 7);
    const size_t bbase = (size_t)ks * 1048576 + (size_t)w * 1024 + (size_t)lane * 16;

    f4 acc = (f4){0.f, 0.f, 0.f, 0.f};
    f4 a0, a1, a2;

    #define LA(SC, AV) AV = *(const f4*)&x[xrow + (size_t)(SC) * 128];

    #define CV(AV, NXT) { h4v hv, lv;                                              \
        _Pragma("unroll")                                                          \
        for (int e = 0; e < 4; ++e) {                                              \
            float f = AV[e]; _Float16 hh = (_Float16)f;                            \
            hv[e] = hh; lv[e] = (_Float16)(f - (float)hh);                         \
        }                                                                          \
        *(h4v*)&abh[NXT][usA] = hv;                                                \
        *(h4v*)&abl[NXT][usA] = lv; }

    #define MM(CUR, SC) {                                                          \
        h8 Bf0 = *(const h8*)((const char*)Bimg + bbase + (size_t)((SC)*4+0)*8192);\
        h8 Bf1 = *(const h8*)((const char*)Bimg + bbase + (size_t)((SC)*4+1)*8192);\
        h8 Bf2 = *(const h8*)((const char*)Bimg + bbase + (size_t)((SC)*4+2)*8192);\
        h8 Bf3 = *(const h8*)((const char*)Bimg + bbase + (size_t)((SC)*4+3)*8192);\
        _Pragma("unroll")                                                          \
        for (int wd = 0; wd < 4; ++wd) {                                           \
            const int sl = ((((wd << 2) + kq) ^ rl) & 15) << 3;                    \
            h8 Ah = *(const h8*)&abh[CUR][rl * 128 + sl];                          \
            h8 Al = *(const h8*)&abl[CUR][rl * 128 + sl];                          \
            h8 Bf = (wd == 0) ? Bf0 : (wd == 1) ? Bf1 : (wd == 2) ? Bf2 : Bf3;     \
            acc = __builtin_amdgcn_mfma_f32_16x16x32_f16(Ah, Bf, acc, 0, 0, 0);    \
            acc = __builtin_amdgcn_mfma_f32_16x16x32_f16(Al, Bf, acc, 0, 0, 0);    \
        } }

    // barrier: LDS-visibility only; A-prefetch loads stay in flight (no vm wait!)
    #define BAR  __builtin_amdgcn_sched_barrier(0);                                \
        asm volatile("s_waitcnt lgkmcnt(0)" ::: "memory");                         \
        __builtin_amdgcn_sched_barrier(0);                                         \
        __builtin_amdgcn_s_barrier();                                              \
        __builtin_amdgcn_sched_barrier(0);

    #define STEP(SC, LAC, AVL, AVC, NXT, CUR)                                      \
        LA(LAC, AVL); CV(AVC, NXT); MM(CUR, SC); BAR

    // prologue: chunks 0,1,2 in flight; stage chunk 0 into buf0
    LA(0, a0); LA(1, a1); LA(2, a2);
    CV(a0, 0);
    BAR
    // steps 0..23 (4 x unroll-6); step s: LA(s+3)->av[s%3], CV av[(s+1)%3]->buf[(s+1)&1], MM buf[s&1]
    for (int s = 0; s < 24; s += 6) {
        STEP(s + 0, s + 3, a0, a1, 1, 0)
        STEP(s + 1, s + 4, a1, a2, 0, 1)
        STEP(s + 2, s + 5, a2, a0, 1, 0)
        STEP(s + 3, s + 6, a0, a1, 0, 1)
        STEP(s + 4, s + 7, a1, a2, 1, 0)
        STEP(s + 5, s + 8, a2, a0, 0, 1)
    }
    // steps 24..29 (LA clamped to last chunk 31)
    STEP(24, 27, a0, a1, 1, 0)
    STEP(25, 28, a1, a2, 0, 1)
    STEP(26, 29, a2, a0, 1, 0)
    STEP(27, 30, a0, a1, 0, 1)
    STEP(28, 31, a1, a2, 1, 0)
    STEP(29, 31, a2, a0, 0, 1)   // dup-load chunk 31 (never consumed)
    // step 30: no LA
    CV(a1, 1); MM(0, 30); BAR
    // step 31: MFMA only
    MM(1, 31);

    // D layout: col=rl, row=kq*4+r; wave w covers cols w*16..w*16+15
    float* Pks = P + (size_t)ks * 4096 * 128;
    #pragma unroll
    for (int r = 0; r < 4; ++r)
        Pks[(size_t)(row0 + kq * 4 + r) * 128 + w * 16 + rl] = acc[r];
}

// ---------------- ksum: X = P[0] + P[1] ----------------
__global__ __launch_bounds__(256) void ksum(const float* __restrict__ P,
                                            float* __restrict__ X) {
    int i = (blockIdx.x * 256 + threadIdx.x) * 4;
    f4 s = *(const f4*)&P[i];
    s += *(const f4*)&P[524288 + i];
    *(f4*)&X[i] = s;
}

// ---------------- K2: mode contraction -> C2 image (pre-swizzled bf16 hi/lo) ----------------
__global__ __launch_bounds__(256) void mode_contract(const float* __restrict__ X,
        const float* __restrict__ w_real, const float* __restrict__ w_imag,
        short* __restrict__ C2h, short* __restrict__ C2l) {
    __shared__ float xr[32][128], xi[32][128];
    __shared__ float wr[128][32], wi[128][32];
    const int m = blockIdx.x, h = blockIdx.y, t = threadIdx.x;
    #pragma unroll
    for (int it = 0; it < 16; ++it) {
        int li = t + it * 256;       // 0..4095
        int b = li >> 7, i = li & 127;
        const float2 v = *(const float2*)&X[(size_t)(b * 128 + i) * 128 + 2 * m];
        xr[b][i] = v.x; xi[b][i] = v.y;
        int i2 = li >> 5, o = li & 31;
        size_t off = ((size_t)((h * 128 + i2) * 32 + o)) * NM + m;
        wr[i2][o] = w_real[off];
        wi[i2][o] = w_imag[off];
    }
    __syncthreads();
    const int o = t & 31;
    const int b0 = (t >> 5) * 4;
    float re[4] = {0.f, 0.f, 0.f, 0.f}, im[4] = {0.f, 0.f, 0.f, 0.f};
    for (int i = 0; i < 128; ++i) {
        float wrv = wr[i][o], wiv = wi[i][o];
        #pragma unroll
        for (int j = 0; j < 4; ++j) {
            float a = xr[b0 + j][i], c = xi[b0 + j][i];
            re[j] += a * wrv - c * wiv;
            im[j] += a * wiv + c * wrv;
        }
    }
    const float alpha = (m == 0) ? (1.0f / (float)S_LEN) : (2.0f / (float)S_LEN);
    const int kc = m >> 4;
    const int lk = (2 * m) & 31;
    #pragma unroll
    for (int j = 0; j < 4; ++j) {
        int row = (b0 + j) * 128 + h * 32 + o;
        float vr = alpha * re[j], vi = alpha * im[j];
        unsigned short hr = f2bf(vr), hi_ = f2bf(vi);
        float lr = vr - bf2f(hr), li_ = vi - bf2f(hi_);
        int rb = row >> 7, lr_ = row & 127;
        size_t ui = ((size_t)(rb * 4 + kc) * 4096 + SW32(lr_, lk)) >> 1;   // uint index
        ((unsigned int*)C2h)[ui] = ((unsigned int)hi_ << 16) | hr;
        ((unsigned int*)C2l)[ui] = ((unsigned int)f2bf(li_) << 16) | f2bf(lr);
    }
}

// ---------------- K3: y = C2[4096][128] * Basis[128][8192], dbuf DMA pipeline ----------------
__global__ __launch_bounds__(256, 2) void idft_mfma(const short* __restrict__ C2h,
        const short* __restrict__ C2l, const short* __restrict__ T1h,
        const short* __restrict__ T1l, float* __restrict__ y) {
    __shared__ short ah[2][4096], al[2][4096];
    __shared__ short bh[2][4096], bl[2][4096];
    const int t = threadIdx.x;
    const int lane = t & 63, wid = t >> 6;
    const int wm = (wid >> 1) * 64, wn = (wid & 1) * 64;
    const int sb = blockIdx.x;                    // col block (s), 0..63
    const int rb = blockIdx.y;                    // row block, 0..31
    f4 acc[4][4];
    #pragma unroll
    for (int i = 0; i < 4; ++i)
        #pragma unroll
        for (int j = 0; j < 4; ++j) acc[i][j] = (f4){0.f, 0.f, 0.f, 0.f};

    #define DMA3(kc, buf)  {                                                       \
        const size_t ta = (size_t)(rb * 4 + (kc)) * 8192;                          \
        const size_t tb = (size_t)(sb * 4 + (kc)) * 8192;                          \
        const int wo = wid * 2048 + lane * 16;                                     \
        glds16((const char*)C2h + ta + wo,        (char*)&ah[buf][0] + wid * 2048);        \
        glds16((const char*)C2h + ta + wo + 1024, (char*)&ah[buf][0] + wid * 2048 + 1024); \
        glds16((const char*)C2l + ta + wo,        (char*)&al[buf][0] + wid * 2048);        \
        glds16((const char*)C2l + ta + wo + 1024, (char*)&al[buf][0] + wid * 2048 + 1024); \
        glds16((const char*)T1h + tb + wo,        (char*)&bh[buf][0] + wid * 2048);        \
        glds16((const char*)T1h + tb + wo + 1024, (char*)&bh[buf][0] + wid * 2048 + 1024); \
        glds16((const char*)T1l + tb + wo,        (char*)&bl[buf][0] + wid * 2048);        \
        glds16((const char*)T1l + tb + wo + 1024, (char*)&bl[buf][0] + wid * 2048 + 1024); }

    DMA3(0, 0);
    __syncthreads();
    #pragma unroll
    for (int kc = 0; kc < 4; ++kc) {
        const int cur = kc & 1;
        if (kc < 3) DMA3(kc + 1, cur ^ 1);
        {
            const int kk = (lane >> 4) * 8, rl = lane & 15;
            s8v Ah[4], Al[4], Bh[4], Bl[4];
            #pragma unroll
            for (int mf = 0; mf < 4; ++mf) {
                int us = SW32(wm + mf * 16 + rl, kk);
                Ah[mf] = *(const s8v*)&ah[cur][us];
                Al[mf] = *(const s8v*)&al[cur][us];
            }
            #pragma unroll
            for (int nf = 0; nf < 4; ++nf) {
                int us = SW32(wn + nf * 16 + rl, kk);
                Bh[nf] = *(const s8v*)&bh[cur][us];
                Bl[nf] = *(const s8v*)&bl[cur][us];
            }
            #pragma unroll
            for (int mf = 0; mf < 4; ++mf)
                #pragma unroll
                for (int nf = 0; nf < 4; ++nf)
                    acc[mf][nf] = __builtin_amdgcn_mfma_f32_16x16x32_bf16(Ah[mf], Bh[nf], acc[mf][nf], 0, 0, 0);
            #pragma unroll
            for (int mf = 0; mf < 4; ++mf)
                #pragma unroll
                for (int nf = 0; nf < 4; ++nf)
                    acc[mf][nf] = __builtin_amdgcn_mfma_f32_16x16x32_bf16(Al[mf], Bh[nf], acc[mf][nf], 0, 0, 0);
            #pragma unroll
            for (int mf = 0; mf < 4; ++mf)
                #pragma unroll
                for (int nf = 0; nf < 4; ++nf)
                    acc[mf][nf] = __builtin_amdgcn_mfma_f32_16x16x32_bf16(Ah[mf], Bl[nf], acc[mf][nf], 0, 0, 0);
        }
        __syncthreads();
    }
    #pragma unroll
    for (int mf = 0; mf < 4; ++mf) {
        int rr = rb * 128 + wm + mf * 16 + (lane >> 4) * 4;
        #pragma unroll
        for (int nf = 0; nf < 4; ++nf) {
            int c = sb * 128 + wn + nf * 16 + (lane & 15);
            #pragma unroll
            for (int r = 0; r < 4; ++r)
                __builtin_nontemporal_store(acc[mf][nf][r], &y[(size_t)(rr + r) * S_LEN + c]);
        }
    }
}

extern "C" void kernel_launch(void* const* d_in, const int* in_sizes, int n_in,
                              void* d_out, int out_size, void* d_ws, size_t ws_size,
                              hipStream_t stream) {
    const float* x      = (const float*)d_in[0];
    const float* w_real = (const float*)d_in[1];
    const float* w_imag = (const float*)d_in[2];
    float* y = (float*)d_out;

    const size_t TBL = (size_t)S_LEN * 128;       // 1M elems
    char* w0 = (char*)d_ws;
    short* T1h     = (short*)w0;                  // 2MB each half
    short* T1l     = T1h + TBL;
    _Float16* Bimg = (_Float16*)(T1l + TBL);      // 2MB fragment-ordered fp16
    float* X       = (float*)(Bimg + TBL);        // 2MB
    short* C2h     = (short*)(X + (size_t)4096 * 128);
    short* C2l     = C2h + (size_t)4096 * 128;
    float* P       = (float*)(C2l + (size_t)4096 * 128);   // 2 x 2MB partials
    const size_t TOTAL = (size_t)((char*)(P + 2 * (size_t)4096 * 128) - w0);  // 16MB
    if (ws_size < TOTAL) {
        fprintf(stderr, "kernel_launch: ws too small (%zu < %zu bytes)\n", ws_size, TOTAL);
        return;
    }

    gen_t1_img<<<(S_LEN * 128) / 256, 256, 0, stream>>>(T1h, T1l);
    gen_b_img<<<(S_LEN * 128) / 256, 256, 0, stream>>>(Bimg);
    dft_fwd_mfma<<<dim3(4096 / 16, 2), 512, 0, stream>>>(x, Bimg, P);
    ksum<<<512, 256, 0, stream>>>(P, X);
    mode_contract<<<dim3(NM, 4), 256, 0, stream>>>(X, w_real, w_imag, C2h, C2l);
    idft_mfma<<<dim3(S_LEN / 128, 4096 / 128), 256, 0, stream>>>(C2h, C2l, T1h, T1l, y);
}